// Round 4
// baseline (135.019 us; speedup 1.0000x reference)
//
#include <hip/hip_runtime.h>

// HyperLayer: y[b, f0/c0] += v * w0 * (wf1*x[b,f1] + wc1*x[b,c1])
// B=16, N=262144, DIM=8192.
// R4: R3's load batch was silently sunk back to per-use loads (VGPR stayed
// 52). Force the 12-float4-per-thread batch to materialize with an asm
// memory clobber between the load phase and the LDS-atomic phase, so the
// wave has ~192 B outstanding instead of ~12 B (load-latency bound at
// 1.3 B/cyc/CU in R2/R3).

#define BATCH 16
#define NPTS 262144
#define DIM 8192
#define SPLITS 32
#define PTS_PER_BLOCK (NPTS / SPLITS)   // 8192
#define BLOCK 512

__global__ __launch_bounds__(BLOCK, 4) void hyper_scatter_kernel(
    const float* __restrict__ x,    // [B, DIM]
    const float* __restrict__ ri,   // [B, N, 2]
    const float* __restrict__ rv,   // [B, N]
    float* __restrict__ partials)   // [B*SPLITS, DIM]
{
    __shared__ float x_s[DIM];   // 32 KB
    __shared__ float y_s[DIM];   // 32 KB

    const int tid   = threadIdx.x;
    const int split = blockIdx.x;
    const int b     = blockIdx.y;

    const size_t base = (size_t)b * NPTS + (size_t)split * PTS_PER_BLOCK;
    const float4* ri4 = (const float4*)(ri + 2 * base);  // 2 points / float4
    const float4* rv4 = (const float4*)(rv + base);      // 4 points / float4

    // ---- Load phase: 12 float4 loads issued before anything can fence them.
    float4 ra[4], rb[4], vv[4];
    #pragma unroll
    for (int k = 0; k < 4; ++k) {
        const int m = tid + k * BLOCK;   // float4 index into rv row-chunk
        ra[k] = ri4[2 * m];              // points 4m, 4m+1
        rb[k] = ri4[2 * m + 1];          // points 4m+2, 4m+3
        vv[k] = rv4[m];
    }

    // ---- Staging (its global loads join the in-flight queue).
    const float4* x4 = (const float4*)(x + (size_t)b * DIM);
    float4* xs4 = (float4*)x_s;
    float4* ys4 = (float4*)y_s;
    #pragma unroll
    for (int i = tid; i < DIM / 4; i += BLOCK) {
        xs4[i] = x4[i];
        ys4[i] = make_float4(0.f, 0.f, 0.f, 0.f);
    }

    // Compiler-level fence: the asm may write memory, so none of the loads
    // above may be re-ordered (sunk) below this point. Forces the batch to
    // stay materialized in VGPRs across the atomic phase.
    asm volatile("" ::: "memory");

    __syncthreads();   // one pipelined drain of all outstanding loads

    auto process = [&](float r0, float r1, float v) {
        float f0 = floorf(r0), c0 = ceilf(r0);
        float f1 = floorf(r1), c1 = ceilf(r1);
        // Per reference: w = 1 - |corner - real|, floor/ceil independently
        // (both corners get weight 1 when floor==ceil).
        float wf0 = 1.0f - (r0 - f0), wc0 = 1.0f - (c0 - r0);
        float wf1 = 1.0f - (r1 - f1), wc1 = 1.0f - (c1 - r1);
        float gx = wf1 * x_s[(int)f1] + wc1 * x_s[(int)c1];
        float vg = v * gx;
        atomicAdd(&y_s[(int)f0], wf0 * vg);
        atomicAdd(&y_s[(int)c0], wc0 * vg);
    };

    #pragma unroll
    for (int k = 0; k < 4; ++k) {
        process(ra[k].x, ra[k].y, vv[k].x);
        process(ra[k].z, ra[k].w, vv[k].y);
        process(rb[k].x, rb[k].y, vv[k].z);
        process(rb[k].z, rb[k].w, vv[k].w);
    }
    __syncthreads();

    // Coalesced float4 store of the partial row (no atomics).
    float4* out4 = (float4*)(partials + ((size_t)b * SPLITS + split) * DIM);
    #pragma unroll
    for (int i = tid; i < DIM / 4; i += BLOCK) {
        out4[i] = ys4[i];
    }
}

// y[b][d] = sum_s partials[b*SPLITS+s][d]; one float4 per thread.
__global__ __launch_bounds__(256) void reduce_partials_kernel(
    const float* __restrict__ partials, float* __restrict__ y)
{
    const int d4 = blockIdx.x * 256 + threadIdx.x;      // [0, B*DIM/4)
    const int b   = d4 / (DIM / 4);
    const int off = d4 % (DIM / 4);
    const float4* p = (const float4*)(partials + (size_t)b * SPLITS * DIM) + off;
    float4 acc = make_float4(0.f, 0.f, 0.f, 0.f);
    #pragma unroll
    for (int s = 0; s < SPLITS; ++s) {
        float4 v = p[(size_t)s * (DIM / 4)];
        acc.x += v.x; acc.y += v.y; acc.z += v.z; acc.w += v.w;
    }
    ((float4*)y)[d4] = acc;
}

// Fallback (ws too small): global-atomic flush.
__global__ __launch_bounds__(BLOCK, 4) void hyper_scatter_atomic_kernel(
    const float* __restrict__ x, const float* __restrict__ ri,
    const float* __restrict__ rv, float* __restrict__ y)
{
    __shared__ float x_s[DIM];
    __shared__ float y_s[DIM];
    const int tid = threadIdx.x, split = blockIdx.x, b = blockIdx.y;
    const float4* x4 = (const float4*)(x + (size_t)b * DIM);
    float4* xs4 = (float4*)x_s;
    float4* ys4 = (float4*)y_s;
    for (int i = tid; i < DIM / 4; i += BLOCK) {
        xs4[i] = x4[i];
        ys4[i] = make_float4(0.f, 0.f, 0.f, 0.f);
    }
    __syncthreads();
    const size_t base = (size_t)b * NPTS + (size_t)split * PTS_PER_BLOCK;
    const float2* idx2 = (const float2*)ri + base;
    const float*  val  = rv + base;
    for (int i = tid; i < PTS_PER_BLOCK; i += BLOCK) {
        float2 r = idx2[i];
        float v  = val[i];
        float f0 = floorf(r.x), c0 = ceilf(r.x);
        float f1 = floorf(r.y), c1 = ceilf(r.y);
        float wf0 = 1.0f - (r.x - f0), wc0 = 1.0f - (c0 - r.x);
        float wf1 = 1.0f - (r.y - f1), wc1 = 1.0f - (c1 - r.y);
        float gx = wf1 * x_s[(int)f1] + wc1 * x_s[(int)c1];
        float vg = v * gx;
        atomicAdd(&y_s[(int)f0], wf0 * vg);
        atomicAdd(&y_s[(int)c0], wc0 * vg);
    }
    __syncthreads();
    float* yrow = y + (size_t)b * DIM;
    for (int i = tid; i < DIM; i += BLOCK) atomicAdd(&yrow[i], y_s[i]);
}

extern "C" void kernel_launch(void* const* d_in, const int* in_sizes, int n_in,
                              void* d_out, int out_size, void* d_ws, size_t ws_size,
                              hipStream_t stream) {
    const float* x  = (const float*)d_in[0];
    const float* ri = (const float*)d_in[1];
    const float* rv = (const float*)d_in[2];
    float* y = (float*)d_out;

    const size_t need = (size_t)BATCH * SPLITS * DIM * sizeof(float);  // 16 MB
    dim3 grid(SPLITS, BATCH);

    if (ws_size >= need) {
        float* partials = (float*)d_ws;
        hyper_scatter_kernel<<<grid, BLOCK, 0, stream>>>(x, ri, rv, partials);
        const int n4 = BATCH * DIM / 4;  // 32768
        reduce_partials_kernel<<<n4 / 256, 256, 0, stream>>>(partials, y);
    } else {
        hipMemsetAsync(y, 0, (size_t)out_size * sizeof(float), stream);
        hyper_scatter_atomic_kernel<<<grid, BLOCK, 0, stream>>>(x, ri, rv, y);
    }
}

// Round 5
// 128.862 us; speedup vs baseline: 1.0478x; 1.0478x over previous
//
#include <hip/hip_runtime.h>

// HyperLayer: y[b, f0/c0] += v * w0 * (wf1*x[b,f1] + wc1*x[b,c1])
// B=16, N=262144, DIM=8192.
// R5: R2=R3=R4 at 55us regardless of load scheduling -> body-bound, not
// load-bound. Theory: default atomicAdd(float*) on LDS is a CAS retry loop
// (ds_read + ds_cmpst_rtn, ~2 serial LDS round-trips per atomic).
// Fix: unsafeAtomicAdd -> native no-return ds_add_f32. Also merge the two
// x gathers into one ds_read2_b32 pair with cndmask correction for the
// integral-index (floor==ceil) case.

#define BATCH 16
#define NPTS 262144
#define DIM 8192
#define SPLITS 32
#define PTS_PER_BLOCK (NPTS / SPLITS)   // 8192
#define BLOCK 512

__global__ __launch_bounds__(BLOCK, 4) void hyper_scatter_kernel(
    const float* __restrict__ x,    // [B, DIM]
    const float* __restrict__ ri,   // [B, N, 2]
    const float* __restrict__ rv,   // [B, N]
    float* __restrict__ partials)   // [B*SPLITS, DIM]
{
    __shared__ float x_s[DIM];   // 32 KB
    __shared__ float y_s[DIM];   // 32 KB

    const int tid   = threadIdx.x;
    const int split = blockIdx.x;
    const int b     = blockIdx.y;

    const float4* x4 = (const float4*)(x + (size_t)b * DIM);
    float4* xs4 = (float4*)x_s;
    float4* ys4 = (float4*)y_s;
    #pragma unroll
    for (int i = tid; i < DIM / 4; i += BLOCK) {
        xs4[i] = x4[i];
        ys4[i] = make_float4(0.f, 0.f, 0.f, 0.f);
    }
    __syncthreads();

    const size_t base = (size_t)b * NPTS + (size_t)split * PTS_PER_BLOCK;
    const float2* idx2 = (const float2*)ri + base;
    const float*  val  = rv + base;

    #pragma unroll 4
    for (int i = tid; i < PTS_PER_BLOCK; i += BLOCK) {
        float2 r = idx2[i];
        float v  = val[i];

        float f0 = floorf(r.x), c0 = ceilf(r.x);
        float f1 = floorf(r.y), c1 = ceilf(r.y);
        // Per reference: w = 1 - |corner - real|, floor/ceil independently
        // (both corners get weight 1 when floor==ceil -> double count).
        float wf0 = 1.0f - (r.x - f0), wc0 = 1.0f - (c0 - r.x);
        float wf1 = 1.0f - (r.y - f1), wc1 = 1.0f - (c1 - r.y);

        // Paired gather: one ds_read2_b32 at {f1, f1+1}; when r.y is exactly
        // integral (c1==f1) the true second operand is x[f1] again.
        int i1 = (int)f1;
        float xa = x_s[i1];
        float xb = x_s[i1 + 1];          // always in range: f1 <= 8182
        xb = (c1 == f1) ? xa : xb;

        float gx = wf1 * xa + wc1 * xb;
        float vg = v * gx;
        // Native ds_add_f32 (no return, no CAS loop).
        unsafeAtomicAdd(&y_s[(int)f0], wf0 * vg);
        unsafeAtomicAdd(&y_s[(int)c0], wc0 * vg);
    }
    __syncthreads();

    // Coalesced float4 store of the partial row (no atomics).
    float4* out4 = (float4*)(partials + ((size_t)b * SPLITS + split) * DIM);
    #pragma unroll
    for (int i = tid; i < DIM / 4; i += BLOCK) {
        out4[i] = ys4[i];
    }
}

// y[b][d] = sum_s partials[b*SPLITS+s][d]; one float4 per thread.
__global__ __launch_bounds__(256) void reduce_partials_kernel(
    const float* __restrict__ partials, float* __restrict__ y)
{
    const int d4 = blockIdx.x * 256 + threadIdx.x;      // [0, B*DIM/4)
    const int b   = d4 / (DIM / 4);
    const int off = d4 % (DIM / 4);
    const float4* p = (const float4*)(partials + (size_t)b * SPLITS * DIM) + off;
    float4 acc = make_float4(0.f, 0.f, 0.f, 0.f);
    #pragma unroll
    for (int s = 0; s < SPLITS; ++s) {
        float4 v = p[(size_t)s * (DIM / 4)];
        acc.x += v.x; acc.y += v.y; acc.z += v.z; acc.w += v.w;
    }
    ((float4*)y)[d4] = acc;
}

// Fallback (ws too small): global-atomic flush.
__global__ __launch_bounds__(BLOCK, 4) void hyper_scatter_atomic_kernel(
    const float* __restrict__ x, const float* __restrict__ ri,
    const float* __restrict__ rv, float* __restrict__ y)
{
    __shared__ float x_s[DIM];
    __shared__ float y_s[DIM];
    const int tid = threadIdx.x, split = blockIdx.x, b = blockIdx.y;
    const float4* x4 = (const float4*)(x + (size_t)b * DIM);
    float4* xs4 = (float4*)x_s;
    float4* ys4 = (float4*)y_s;
    for (int i = tid; i < DIM / 4; i += BLOCK) {
        xs4[i] = x4[i];
        ys4[i] = make_float4(0.f, 0.f, 0.f, 0.f);
    }
    __syncthreads();
    const size_t base = (size_t)b * NPTS + (size_t)split * PTS_PER_BLOCK;
    const float2* idx2 = (const float2*)ri + base;
    const float*  val  = rv + base;
    for (int i = tid; i < PTS_PER_BLOCK; i += BLOCK) {
        float2 r = idx2[i];
        float v  = val[i];
        float f0 = floorf(r.x), c0 = ceilf(r.x);
        float f1 = floorf(r.y), c1 = ceilf(r.y);
        float wf0 = 1.0f - (r.x - f0), wc0 = 1.0f - (c0 - r.x);
        float wf1 = 1.0f - (r.y - f1), wc1 = 1.0f - (c1 - r.y);
        float gx = wf1 * x_s[(int)f1] + wc1 * x_s[(int)c1];
        float vg = v * gx;
        unsafeAtomicAdd(&y_s[(int)f0], wf0 * vg);
        unsafeAtomicAdd(&y_s[(int)c0], wc0 * vg);
    }
    __syncthreads();
    float* yrow = y + (size_t)b * DIM;
    for (int i = tid; i < DIM; i += BLOCK) atomicAdd(&yrow[i], y_s[i]);
}

extern "C" void kernel_launch(void* const* d_in, const int* in_sizes, int n_in,
                              void* d_out, int out_size, void* d_ws, size_t ws_size,
                              hipStream_t stream) {
    const float* x  = (const float*)d_in[0];
    const float* ri = (const float*)d_in[1];
    const float* rv = (const float*)d_in[2];
    float* y = (float*)d_out;

    const size_t need = (size_t)BATCH * SPLITS * DIM * sizeof(float);  // 16 MB
    dim3 grid(SPLITS, BATCH);

    if (ws_size >= need) {
        float* partials = (float*)d_ws;
        hyper_scatter_kernel<<<grid, BLOCK, 0, stream>>>(x, ri, rv, partials);
        const int n4 = BATCH * DIM / 4;  // 32768
        reduce_partials_kernel<<<n4 / 256, 256, 0, stream>>>(partials, y);
    } else {
        hipMemsetAsync(y, 0, (size_t)out_size * sizeof(float), stream);
        hyper_scatter_atomic_kernel<<<grid, BLOCK, 0, stream>>>(x, ri, rv, y);
    }
}